// Round 1
// baseline (1404.047 us; speedup 1.0000x reference)
//
#include <hip/hip_runtime.h>

#define DIM 128
#define NLEV 8

// class id: AND gates (gate==1) at level l -> l-1 ; NOT gates (gate==2) -> 8 + l-1
__device__ __forceinline__ int cls_of(int g, int l) {
    if (l < 1 || l > NLEV) return -1;
    if (g == 1) return l - 1;
    if (g == 2) return NLEV + (l - 1);
    return -1;
}

__global__ void deg_count_kernel(const int* __restrict__ dstv, float* __restrict__ deg, int E) {
    int i = blockIdx.x * blockDim.x + threadIdx.x;
    if (i < E) atomicAdd(&deg[dstv[i]], 1.0f);
}

__global__ void deg_finalize_kernel(const float* __restrict__ deg, float* __restrict__ dis,
                                    float* __restrict__ inv, int n) {
    int i = blockIdx.x * blockDim.x + threadIdx.x;
    if (i < n) {
        float d = deg[i] + 1.0f;
        dis[i] = rsqrtf(d);
        inv[i] = 1.0f / d;
    }
}

__global__ void build_node_lists_kernel(const int* __restrict__ gate, const int* __restrict__ level,
                                        int* __restrict__ nlist, int* __restrict__ ncnt, int n) {
    int i = blockIdx.x * blockDim.x + threadIdx.x;
    if (i >= n) return;
    int c = cls_of(gate[i], level[i]);
    if (c < 0) return;
    int p = atomicAdd(&ncnt[c], 1);
    nlist[c * n + p] = i;
}

__global__ void build_edge_lists_kernel(const int* __restrict__ dstv, const int* __restrict__ gate,
                                        const int* __restrict__ level, int* __restrict__ elist,
                                        int* __restrict__ ecnt, int E) {
    int i = blockIdx.x * blockDim.x + threadIdx.x;
    if (i >= E) return;
    int d = dstv[i];
    int c = cls_of(gate[d], level[d]);
    if (c < 0) return;
    int p = atomicAdd(&ecnt[c], 1);
    elist[c * E + p] = i;
}

// out[i][j] = act( sum_k in0[i][k]*W[k][j] (+ sum_k in1[i][k]*W[128+k][j]) + b[j] )
// ACT: 0 none, 1 relu.  BIAS: 0/1.
template <int NSRC, int ACT, int BIAS>
__global__ __launch_bounds__(DIM) void mm_kernel(const float* __restrict__ in0,
                                                 const float* __restrict__ in1,
                                                 const float* __restrict__ W,
                                                 const float* __restrict__ b,
                                                 float* __restrict__ out, int n) {
    const int R = 8;
    int row0 = blockIdx.x * R;
    int j = threadIdx.x;
    float acc[R];
#pragma unroll
    for (int r = 0; r < R; r++) acc[r] = 0.f;
    for (int k = 0; k < DIM; k += 4) {
        float w0 = W[(k + 0) * DIM + j];
        float w1 = W[(k + 1) * DIM + j];
        float w2 = W[(k + 2) * DIM + j];
        float w3 = W[(k + 3) * DIM + j];
#pragma unroll
        for (int r = 0; r < R; r++) {
            const float4 a = *reinterpret_cast<const float4*>(in0 + (size_t)(row0 + r) * DIM + k);
            acc[r] = fmaf(a.x, w0, acc[r]);
            acc[r] = fmaf(a.y, w1, acc[r]);
            acc[r] = fmaf(a.z, w2, acc[r]);
            acc[r] = fmaf(a.w, w3, acc[r]);
        }
    }
    if (NSRC == 2) {
        for (int k = 0; k < DIM; k += 4) {
            float w0 = W[(DIM + k + 0) * DIM + j];
            float w1 = W[(DIM + k + 1) * DIM + j];
            float w2 = W[(DIM + k + 2) * DIM + j];
            float w3 = W[(DIM + k + 3) * DIM + j];
#pragma unroll
            for (int r = 0; r < R; r++) {
                const float4 a = *reinterpret_cast<const float4*>(in1 + (size_t)(row0 + r) * DIM + k);
                acc[r] = fmaf(a.x, w0, acc[r]);
                acc[r] = fmaf(a.y, w1, acc[r]);
                acc[r] = fmaf(a.z, w2, acc[r]);
                acc[r] = fmaf(a.w, w3, acc[r]);
            }
        }
    }
    float bias = BIAS ? b[j] : 0.f;
#pragma unroll
    for (int r = 0; r < R; r++) {
        float v = acc[r] + bias;
        if (ACT == 1) v = fmaxf(v, 0.f);
        out[(size_t)(row0 + r) * DIM + j] = v;
    }
}

// x2[n][j] = inv[n]*x[n][j] + gcn_b[j]
__global__ void gcn_self_kernel(const float* __restrict__ x, const float* __restrict__ inv,
                                const float* __restrict__ gb, float* __restrict__ x2, int total) {
    int i = blockIdx.x * blockDim.x + threadIdx.x;
    if (i >= total) return;
    int nidx = i >> 7;
    int j = i & (DIM - 1);
    x2[i] = inv[nidx] * x[i] + gb[j];
}

// x2[dst] += dis[src]*dis[dst]*x[src]   (all edges)
__global__ __launch_bounds__(DIM) void gcn_scatter_kernel(const float* __restrict__ x,
                                                          const float* __restrict__ dis,
                                                          const int* __restrict__ srcv,
                                                          const int* __restrict__ dstv,
                                                          float* __restrict__ x2, int E) {
    int j = threadIdx.x;
    for (int e = blockIdx.x; e < E; e += gridDim.x) {
        int s = srcv[e], d = dstv[e];
        float coef = dis[s] * dis[d];
        atomicAdd(&x2[(size_t)d * DIM + j], coef * x[(size_t)s * DIM + j]);
    }
}

__global__ __launch_bounds__(DIM) void list_zero_kernel(float* __restrict__ buf,
                                                        const int* __restrict__ nlist,
                                                        const int* __restrict__ ncnt, int c, int n) {
    int cnt = ncnt[c];
    for (int idx = blockIdx.x; idx < cnt; idx += gridDim.x) {
        int node = nlist[c * n + idx];
        buf[(size_t)node * DIM + threadIdx.x] = 0.f;
    }
}

__global__ __launch_bounds__(DIM) void list_copy_kernel(float* __restrict__ dstbuf,
                                                        const float* __restrict__ srcbuf,
                                                        const int* __restrict__ nlist,
                                                        const int* __restrict__ ncnt, int c, int n) {
    int cnt = ncnt[c];
    for (int idx = blockIdx.x; idx < cnt; idx += gridDim.x) {
        int node = nlist[c * n + idx];
        dstbuf[(size_t)node * DIM + threadIdx.x] = srcbuf[(size_t)node * DIM + threadIdx.x];
    }
}

// For each edge e in class c: m = relu( in0[src]@W[0:128] (+ in1[src]@W[128:256]) + b )
// agg[dst] += m   (atomic)
template <int NSRC>
__global__ __launch_bounds__(DIM) void scatter_msg_kernel(const float* __restrict__ in0,
                                                          const float* __restrict__ in1,
                                                          const float* __restrict__ W,
                                                          const float* __restrict__ b,
                                                          float* __restrict__ agg,
                                                          const int* __restrict__ srcv,
                                                          const int* __restrict__ dstv,
                                                          const int* __restrict__ elist,
                                                          const int* __restrict__ ecnt, int c, int E) {
    int cnt = ecnt[c];
    int j = threadIdx.x;
    for (int idx = blockIdx.x; idx < cnt; idx += gridDim.x) {
        int e = elist[c * E + idx];
        int s = srcv[e], d = dstv[e];
        float acc = b[j];
        const float* row0 = in0 + (size_t)s * DIM;
        for (int k = 0; k < DIM; k += 4) {
            float4 a = *reinterpret_cast<const float4*>(row0 + k);
            acc = fmaf(a.x, W[(k + 0) * DIM + j], acc);
            acc = fmaf(a.y, W[(k + 1) * DIM + j], acc);
            acc = fmaf(a.z, W[(k + 2) * DIM + j], acc);
            acc = fmaf(a.w, W[(k + 3) * DIM + j], acc);
        }
        if (NSRC == 2) {
            const float* row1 = in1 + (size_t)s * DIM;
            for (int k = 0; k < DIM; k += 4) {
                float4 a = *reinterpret_cast<const float4*>(row1 + k);
                acc = fmaf(a.x, W[(DIM + k + 0) * DIM + j], acc);
                acc = fmaf(a.y, W[(DIM + k + 1) * DIM + j], acc);
                acc = fmaf(a.z, W[(DIM + k + 2) * DIM + j], acc);
                acc = fmaf(a.w, W[(DIM + k + 3) * DIM + j], acc);
            }
        }
        acc = fmaxf(acc, 0.f);
        atomicAdd(&agg[(size_t)d * DIM + j], acc);
    }
}

// hs[n] = relu( hs[n]@W[0:128] + agg[n]@W[128:256] + b )   (in place, masked nodes)
__global__ __launch_bounds__(DIM) void update_and_kernel(float* __restrict__ hs,
                                                         const float* __restrict__ agg,
                                                         const float* __restrict__ W,
                                                         const float* __restrict__ b,
                                                         const int* __restrict__ nlist,
                                                         const int* __restrict__ ncnt, int c, int n) {
    int cnt = ncnt[c];
    int j = threadIdx.x;
    for (int idx = blockIdx.x; idx < cnt; idx += gridDim.x) {
        int node = nlist[c * n + idx];
        const float* r0 = hs + (size_t)node * DIM;
        const float* r1 = agg + (size_t)node * DIM;
        float acc = b[j];
        for (int k = 0; k < DIM; k += 4) {
            float4 a = *reinterpret_cast<const float4*>(r0 + k);
            acc = fmaf(a.x, W[(k + 0) * DIM + j], acc);
            acc = fmaf(a.y, W[(k + 1) * DIM + j], acc);
            acc = fmaf(a.z, W[(k + 2) * DIM + j], acc);
            acc = fmaf(a.w, W[(k + 3) * DIM + j], acc);
        }
        for (int k = 0; k < DIM; k += 4) {
            float4 a = *reinterpret_cast<const float4*>(r1 + k);
            acc = fmaf(a.x, W[(DIM + k + 0) * DIM + j], acc);
            acc = fmaf(a.y, W[(DIM + k + 1) * DIM + j], acc);
            acc = fmaf(a.z, W[(DIM + k + 2) * DIM + j], acc);
            acc = fmaf(a.w, W[(DIM + k + 3) * DIM + j], acc);
        }
        __syncthreads();  // wave0 reads cols 64..127 (uniform float4) before wave1 overwrites them
        hs[(size_t)node * DIM + j] = fmaxf(acc, 0.f);
    }
}

// hs[n] = tanh( agg[n]@W + b )   (masked nodes; reads only agg -> no barrier)
__global__ __launch_bounds__(DIM) void update_not_kernel(float* __restrict__ hs,
                                                         const float* __restrict__ agg,
                                                         const float* __restrict__ W,
                                                         const float* __restrict__ b,
                                                         const int* __restrict__ nlist,
                                                         const int* __restrict__ ncnt, int c, int n) {
    int cnt = ncnt[c];
    int j = threadIdx.x;
    for (int idx = blockIdx.x; idx < cnt; idx += gridDim.x) {
        int node = nlist[c * n + idx];
        const float* r1 = agg + (size_t)node * DIM;
        float acc = b[j];
        for (int k = 0; k < DIM; k += 4) {
            float4 a = *reinterpret_cast<const float4*>(r1 + k);
            acc = fmaf(a.x, W[(k + 0) * DIM + j], acc);
            acc = fmaf(a.y, W[(k + 1) * DIM + j], acc);
            acc = fmaf(a.z, W[(k + 2) * DIM + j], acc);
            acc = fmaf(a.w, W[(k + 3) * DIM + j], acc);
        }
        hs[(size_t)node * DIM + j] = tanhf(acc);
    }
}

// hf[dst] += sigmoid(dot(zs[src], zt[dst])) * zs[src]   (all edges, one wave per edge)
__global__ __launch_bounds__(256) void dec_scatter_kernel(const float* __restrict__ zs,
                                                          const float* __restrict__ zt,
                                                          const int* __restrict__ srcv,
                                                          const int* __restrict__ dstv,
                                                          float* __restrict__ hf, int E) {
    int wid = threadIdx.x >> 6;
    int lane = threadIdx.x & 63;
    int wstride = gridDim.x * 4;
    for (int e = blockIdx.x * 4 + wid; e < E; e += wstride) {
        int s = srcv[e], d = dstv[e];
        float a0 = zs[(size_t)s * DIM + lane];
        float a1 = zs[(size_t)s * DIM + lane + 64];
        float b0 = zt[(size_t)d * DIM + lane];
        float b1 = zt[(size_t)d * DIM + lane + 64];
        float p = a0 * b0 + a1 * b1;
#pragma unroll
        for (int off = 32; off > 0; off >>= 1) p += __shfl_xor(p, off, 64);
        float w = 1.f / (1.f + __expf(-p));
        atomicAdd(&hf[(size_t)d * DIM + lane], w * a0);
        atomicAdd(&hf[(size_t)d * DIM + lane + 64], w * a1);
    }
}

extern "C" void kernel_launch(void* const* d_in, const int* in_sizes, int n_in,
                              void* d_out, int out_size, void* d_ws, size_t ws_size,
                              hipStream_t stream) {
    const float* hs_init = (const float*)d_in[0];
    const int* ei = (const int*)d_in[1];
    const int* gate = (const int*)d_in[2];
    const int* level = (const int*)d_in[3];
    const float* gcn_w = (const float*)d_in[4];
    const float* gcn_b = (const float*)d_in[5];
    const float* mu_w = (const float*)d_in[6];
    const float* mu_b = (const float*)d_in[7];
    // d_in[8], d_in[9]: ls_w, ls_b -> dead code in eval mode, skipped
    const float* as_w = (const float*)d_in[10];
    const float* as_b = (const float*)d_in[11];
    const float* ns_w = (const float*)d_in[12];
    const float* ns_b = (const float*)d_in[13];
    const float* af_w = (const float*)d_in[14];
    const float* af_b = (const float*)d_in[15];
    const float* nf_w = (const float*)d_in[16];
    const float* nf_b = (const float*)d_in[17];
    const float* ua_w = (const float*)d_in[18];
    const float* ua_b = (const float*)d_in[19];
    const float* un_w = (const float*)d_in[20];
    const float* un_b = (const float*)d_in[21];
    const float* dec_ws_w = (const float*)d_in[22];
    const float* dec_wt_w = (const float*)d_in[23];

    const int n = in_sizes[0] / DIM;  // 32768
    const int E = in_sizes[1] / 2;    // 65536
    const int* srcv = ei;
    const int* dstv = ei + E;

    float* hs = (float*)d_out;                 // [n, DIM]
    float* hf_out = hs + (size_t)n * DIM;      // [n, DIM]

    char* wp = (char*)d_ws;
    float* x = (float*)wp;      wp += (size_t)n * DIM * 4;
    float* x2 = (float*)wp;     wp += (size_t)n * DIM * 4;  // also agg, then zt
    float* hf = (float*)wp;     wp += (size_t)n * DIM * 4;
    float* deg = (float*)wp;    wp += (size_t)n * 4;
    float* dis = (float*)wp;    wp += (size_t)n * 4;
    float* inv = (float*)wp;    wp += (size_t)n * 4;
    int* ncnt = (int*)wp;       wp += 16 * 4;
    int* ecnt = (int*)wp;       wp += 16 * 4;
    int* nlist = (int*)wp;      wp += (size_t)16 * n * 4;
    int* elist = (int*)wp;      wp += (size_t)16 * E * 4;

    hipMemsetAsync(deg, 0, (size_t)n * 4, stream);
    hipMemsetAsync(ncnt, 0, 16 * 4, stream);
    hipMemsetAsync(ecnt, 0, 16 * 4, stream);
    hipMemsetAsync(hf, 0, (size_t)n * DIM * 4, stream);

    deg_count_kernel<<<(E + 255) / 256, 256, 0, stream>>>(dstv, deg, E);
    deg_finalize_kernel<<<(n + 255) / 256, 256, 0, stream>>>(deg, dis, inv, n);
    build_node_lists_kernel<<<(n + 255) / 256, 256, 0, stream>>>(gate, level, nlist, ncnt, n);
    build_edge_lists_kernel<<<(E + 255) / 256, 256, 0, stream>>>(dstv, gate, level, elist, ecnt, E);

    // --- GCN encoder ---
    mm_kernel<1, 0, 0><<<n / 8, DIM, 0, stream>>>(hs_init, nullptr, gcn_w, nullptr, x, n);
    gcn_self_kernel<<<(n * DIM + 255) / 256, 256, 0, stream>>>(x, inv, gcn_b, x2, n * DIM);
    gcn_scatter_kernel<<<2048, DIM, 0, stream>>>(x, dis, srcv, dstv, x2, E);
    // hs = mu
    mm_kernel<1, 0, 1><<<n / 8, DIM, 0, stream>>>(x2, nullptr, mu_w, mu_b, hs, n);

    // --- level-wise propagation ---
    float* agg = x2;
    for (int l = 1; l <= NLEV; l++) {
        int cA = l - 1;
        int cN = NLEV + l - 1;
        // AND structural
        list_zero_kernel<<<256, DIM, 0, stream>>>(agg, nlist, ncnt, cA, n);
        scatter_msg_kernel<1><<<1024, DIM, 0, stream>>>(hs, nullptr, as_w, as_b, agg, srcv, dstv, elist, ecnt, cA, E);
        update_and_kernel<<<256, DIM, 0, stream>>>(hs, agg, ua_w, ua_b, nlist, ncnt, cA, n);
        // AND functional
        list_zero_kernel<<<256, DIM, 0, stream>>>(agg, nlist, ncnt, cA, n);
        scatter_msg_kernel<2><<<1024, DIM, 0, stream>>>(hs, hf, af_w, af_b, agg, srcv, dstv, elist, ecnt, cA, E);
        list_copy_kernel<<<256, DIM, 0, stream>>>(hf, agg, nlist, ncnt, cA, n);
        // NOT structural
        list_zero_kernel<<<256, DIM, 0, stream>>>(agg, nlist, ncnt, cN, n);
        scatter_msg_kernel<1><<<1024, DIM, 0, stream>>>(hs, nullptr, ns_w, ns_b, agg, srcv, dstv, elist, ecnt, cN, E);
        update_not_kernel<<<256, DIM, 0, stream>>>(hs, agg, un_w, un_b, nlist, ncnt, cN, n);
        // NOT functional
        list_zero_kernel<<<256, DIM, 0, stream>>>(agg, nlist, ncnt, cN, n);
        scatter_msg_kernel<1><<<1024, DIM, 0, stream>>>(hf, nullptr, nf_w, nf_b, agg, srcv, dstv, elist, ecnt, cN, E);
        list_copy_kernel<<<256, DIM, 0, stream>>>(hf, agg, nlist, ncnt, cN, n);
    }

    // --- decoder ---
    float* zs = x;
    float* zt = x2;
    mm_kernel<1, 0, 0><<<n / 8, DIM, 0, stream>>>(hs, nullptr, dec_ws_w, nullptr, zs, n);
    mm_kernel<1, 0, 0><<<n / 8, DIM, 0, stream>>>(hs, nullptr, dec_wt_w, nullptr, zt, n);
    hipMemsetAsync(hf_out, 0, (size_t)n * DIM * 4, stream);
    dec_scatter_kernel<<<1024, 256, 0, stream>>>(zs, zt, srcv, dstv, hf_out, E);
}